// Round 1
// baseline (1992.788 us; speedup 1.0000x reference)
//
#include <hip/hip_runtime.h>
#include <math.h>

#define T_DATA 10000
#define E_NO 2000
#define I_NO 500
#define SUB_NO 64
#define KERN_LEN 201
#define PAD 100
#define MAXNNZ 16

// ---------------- K0: extract one-hot assignments ----------------
__global__ void assign_kernel(const float* __restrict__ Ce, const float* __restrict__ Ci,
                              int* __restrict__ ae, int* __restrict__ ai) {
    int idx = blockIdx.x * 256 + threadIdx.x;
    if (idx < E_NO) {
        int a = 0;
        for (int s = 0; s < SUB_NO; ++s)
            if (Ce[(size_t)s * E_NO + idx] != 0.0f) a = s;
        ae[idx] = a;
    } else if (idx < E_NO + I_NO) {
        int i = idx - E_NO;
        int a = 0;
        for (int s = 0; s < SUB_NO; ++s)
            if (Ci[(size_t)s * I_NO + i] != 0.0f) a = s;
        ai[i] = a;
    }
}

// ---------------- K1: drive[t][s] = cnt_e*we[s] + cnt_i*wi[s] ----------------
__global__ void drive_kernel(const float* __restrict__ Se, const float* __restrict__ Si,
                             const float* __restrict__ wraw,
                             const int* __restrict__ ae, const int* __restrict__ ai,
                             float* __restrict__ drive) {
    __shared__ float be[SUB_NO];
    __shared__ float bi[SUB_NO];
    int t = blockIdx.x;
    int tid = threadIdx.x;
    if (tid < SUB_NO) { be[tid] = 0.0f; bi[tid] = 0.0f; }
    __syncthreads();
    const float* se = Se + (size_t)t * E_NO;
    for (int e = tid; e < E_NO; e += 256) {
        if (se[e] != 0.0f) atomicAdd(&be[ae[e]], 1.0f);
    }
    const float* si = Si + (size_t)t * I_NO;
    for (int i = tid; i < I_NO; i += 256) {
        if (si[i] != 0.0f) atomicAdd(&bi[ai[i]], 1.0f);
    }
    __syncthreads();
    if (tid < SUB_NO) {
        // weights per subunit; counts are exact integers so only the final
        // mul/mul/add order matters (matches reference elementwise form).
        float we = (float)exp((double)wraw[2 * tid]);
        float wi = -(float)exp((double)wraw[2 * tid + 1]);
        drive[(size_t)t * SUB_NO + tid] =
            __fadd_rn(__fmul_rn(be[tid], we), __fmul_rn(bi[tid], wi));
    }
}

// ---------------- K2: sequential scan, one wave, lane = subunit ----------------
__global__ void __launch_bounds__(64, 1)
scan_kernel(const float* __restrict__ drive, const float* __restrict__ Cden,
            const float* __restrict__ decay_raw, const float* __restrict__ thr_raw,
            const float* __restrict__ prop_raw,
            float* __restrict__ spk_out, float* __restrict__ spk0) {
    __shared__ float prop_l[SUB_NO];
    int s = threadIdx.x;
    prop_l[s] = (float)exp((double)prop_raw[s]);
    __syncthreads();

    // decay = sigmoid(decay_raw): follow the f32 pipeline, each op correctly rounded
    float em = (float)exp(-(double)decay_raw[s]);
    float den = __fadd_rn(1.0f, em);
    float decay = (float)(1.0 / (double)den);
    float thr = -(float)exp((double)thr_raw[s]);

    // build sparse row list of C_den[s][:], ascending j, statically indexed
    unsigned long long rowmask = 0ull;
    for (int j = 0; j < SUB_NO; ++j)
        if (Cden[(size_t)s * SUB_NO + j] != 0.0f) rowmask |= (1ull << j);

    float pj[MAXNNZ];
    int jj[MAXNNZ];
    unsigned long long rm = rowmask;
#pragma unroll
    for (int k = 0; k < MAXNNZ; ++k) {
        int j = rm ? (int)__builtin_ctzll(rm) : 0;
        pj[k] = rm ? prop_l[j] : 0.0f;  // empty slots add exact 0.0f (no-op)
        jj[k] = j;
        rm &= rm - 1ull;
    }

    float V = 0.0f, spk = 0.0f;
    unsigned long long mask = 0ull;

    // 8-deep drive prefetch (single wave cannot hide HBM latency otherwise)
    float dbuf[8];
#pragma unroll
    for (int k = 0; k < 8; ++k) dbuf[k] = drive[(size_t)k * SUB_NO + s];

    for (int tb = 0; tb < T_DATA; tb += 8) {
        float dn[8];
#pragma unroll
        for (int k = 0; k < 8; ++k) {
            int tt = tb + 8 + k;
            dn[k] = (tt < T_DATA) ? drive[(size_t)tt * SUB_NO + s] : 0.0f;
        }
#pragma unroll
        for (int k = 0; k < 8; ++k) {
            int t = tb + k;
            // coupling from PREVIOUS spike mask, ascending-j sequential f32 adds
            float acc = 0.0f;
#pragma unroll
            for (int q = 0; q < MAXNNZ; ++q) {
                float c = ((mask >> jj[q]) & 1ull) ? pj[q] : 0.0f;
                acc = __fadd_rn(acc, c);
            }
            // V = V*(1-spk)*decay + d_t + coupling  (exact reference op order)
            float a = __fmul_rn(V, __fsub_rn(1.0f, spk));
            float b = __fmul_rn(a, decay);
            float cc = __fadd_rn(b, dbuf[k]);
            V = __fadd_rn(cc, acc);
            float sv = __fadd_rn(V, thr);
            spk = (sv > 0.0f) ? 1.0f : 0.0f;  // heaviside(0)=0 -> strict >
            spk_out[(size_t)t * SUB_NO + s] = spk;
            if (s == 0) spk0[t] = spk;
            mask = __ballot(sv > 0.0f);
        }
#pragma unroll
        for (int k = 0; k < 8; ++k) dbuf[k] = dn[k];
    }
}

// ---------------- K3: 201-tap conv of spk0 ----------------
__global__ void conv_kernel(const float* __restrict__ spk0, float* __restrict__ out) {
    __shared__ float kern_s[KERN_LEN];
    __shared__ float x_s[256 + 2 * PAD];
    int tid = threadIdx.x;
    int t0 = blockIdx.x * 256;

    float e2 = (float)exp(2.0);
    float e075 = (float)exp(0.75);
    for (int m = tid; m < KERN_LEN; m += 256) {
        float tt = (float)m / e2;
        kern_s[m] = __fmul_rn(__fmul_rn(tt, expf(-tt)), e075);
    }
    for (int k = tid; k < 256 + 2 * PAD; k += 256) {
        int idx = t0 - PAD + k;
        x_s[k] = (idx >= 0 && idx < T_DATA) ? spk0[idx] : 0.0f;
    }
    __syncthreads();

    int t = t0 + tid;
    if (t < T_DATA) {
        float acc = 0.0f;
        // final[t] = sum_m kern[m] * spk0[t + PAD - m]; x_s[k] = spk0[t0-PAD+k]
        for (int m = 0; m < KERN_LEN; ++m)
            acc += kern_s[m] * x_s[tid + 2 * PAD - m];
        out[t] = acc;
    }
}

extern "C" void kernel_launch(void* const* d_in, const int* in_sizes, int n_in,
                              void* d_out, int out_size, void* d_ws, size_t ws_size,
                              hipStream_t stream) {
    const float* S_e      = (const float*)d_in[0];
    const float* S_i      = (const float*)d_in[1];
    const float* C_den    = (const float*)d_in[2];
    const float* C_syn_e  = (const float*)d_in[3];
    const float* C_syn_i  = (const float*)d_in[4];
    const float* w_raw    = (const float*)d_in[5];
    const float* dec_raw  = (const float*)d_in[6];
    const float* thr_raw  = (const float*)d_in[7];
    const float* prop_raw = (const float*)d_in[8];

    float* out = (float*)d_out;              // [0,10000) final, [10000,650000) spk_out
    float* ws = (float*)d_ws;
    float* drive = ws;                        // 640000 floats
    int*   ae    = (int*)(ws + 640000);       // 2000 ints
    int*   ai    = (int*)(ws + 642000);       // 500 ints
    float* spk0  = ws + 642500;               // 10000 floats

    assign_kernel<<<(E_NO + I_NO + 255) / 256, 256, 0, stream>>>(C_syn_e, C_syn_i, ae, ai);
    drive_kernel<<<T_DATA, 256, 0, stream>>>(S_e, S_i, w_raw, ae, ai, drive);
    scan_kernel<<<1, 64, 0, stream>>>(drive, C_den, dec_raw, thr_raw, prop_raw,
                                      out + T_DATA, spk0);
    conv_kernel<<<(T_DATA + 255) / 256, 256, 0, stream>>>(spk0, out);
}

// Round 2
// 610.420 us; speedup vs baseline: 3.2646x; 3.2646x over previous
//
#include <hip/hip_runtime.h>
#include <math.h>

#define T_DATA 10000
#define E_NO 2000
#define I_NO 500
#define SUB_NO 64
#define KERN_LEN 201
#define PAD 100
#define NBLK 314              // 314*32 = 10048 >= 10000 steps (tail garbage unread)

// ws layout (floats):
//   [0, 640000)      drive [t][64]
//   [640000,642000)  ae (int)
//   [642000,642500)  ai (int)
//   packed spike words: at ws+642500 if ws is big enough, else ALIASED onto
//   drive base (packed word w overlaps drive row t=w, which is dead by the
//   time word w is written at step 32w+31; prefetch for t' is issued ~48
//   steps before step t', still >> w). Both placements are race-free.

// ---------------- K0: extract one-hot assignments ----------------
__global__ void assign_kernel(const float* __restrict__ Ce, const float* __restrict__ Ci,
                              int* __restrict__ ae, int* __restrict__ ai) {
    int idx = blockIdx.x * 256 + threadIdx.x;
    if (idx < E_NO) {
        int a = 0;
        for (int s = 0; s < SUB_NO; ++s)
            if (Ce[(size_t)s * E_NO + idx] != 0.0f) a = s;
        ae[idx] = a;
    } else if (idx < E_NO + I_NO) {
        int i = idx - E_NO;
        int a = 0;
        for (int s = 0; s < SUB_NO; ++s)
            if (Ci[(size_t)s * I_NO + i] != 0.0f) a = s;
        ai[i] = a;
    }
}

// ---------------- K1: drive[t][s] = cnt_e*we[s] + cnt_i*wi[s] ----------------
__global__ void drive_kernel(const float* __restrict__ Se, const float* __restrict__ Si,
                             const float* __restrict__ wraw,
                             const int* __restrict__ ae, const int* __restrict__ ai,
                             float* __restrict__ drive) {
    __shared__ float be[SUB_NO];
    __shared__ float bi[SUB_NO];
    int t = blockIdx.x;
    int tid = threadIdx.x;
    if (tid < SUB_NO) { be[tid] = 0.0f; bi[tid] = 0.0f; }
    __syncthreads();
    const float* se = Se + (size_t)t * E_NO;
    for (int e = tid; e < E_NO; e += 256) {
        if (se[e] != 0.0f) atomicAdd(&be[ae[e]], 1.0f);
    }
    const float* si = Si + (size_t)t * I_NO;
    for (int i = tid; i < I_NO; i += 256) {
        if (si[i] != 0.0f) atomicAdd(&bi[ai[i]], 1.0f);
    }
    __syncthreads();
    if (tid < SUB_NO) {
        float we = (float)exp((double)wraw[2 * tid]);
        float wi = -(float)exp((double)wraw[2 * tid + 1]);
        drive[(size_t)t * SUB_NO + tid] =
            __fadd_rn(__fmul_rn(be[tid], we), __fmul_rn(bi[tid], wi));
    }
}

// ---------------- K2 fast path: uniform prop, coupling = f(popcount) ----------------
// f(k) = sequential ascending f32 sum of k copies of p (depends only on k when
// all prop equal) -> register table + cndmask binary tree, static indices only.
template<int KBITS>
__device__ __forceinline__ void scan_fast(const float* drive, unsigned int* packed,
                                          unsigned long long rowmask, float p0,
                                          float decay, float thr, int s) {
    constexpr int NT = 1 << KBITS;
    float tbl[NT];
    {
        float f = 0.0f;
#pragma unroll
        for (int i = 0; i < NT; ++i) { tbl[i] = f; f = __fadd_rn(f, p0); }
    }

    float V = 0.0f;
    bool sp = false;
    unsigned long long mask = 0ull;
    unsigned int bits = 0u;

    const float* dp = drive + s;
    unsigned int* pw = packed + s;

    float bufA[32], bufB[32];
#pragma unroll
    for (int k = 0; k < 32; ++k) bufA[k] = dp[(size_t)k * SUB_NO];

    auto STEP = [&](float d, unsigned int bit) {
        unsigned long long m = mask & rowmask;
        int kc = (int)__popcll(m);
        // binary-tree select: acc = tbl[kc]
        float v[NT / 2];
#pragma unroll
        for (int i = 0; i < NT / 2; ++i) v[i] = (kc & 1) ? tbl[2 * i + 1] : tbl[2 * i];
#pragma unroll
        for (int lvl = 1; lvl < KBITS; ++lvl) {
            const int n = NT >> (lvl + 1);
#pragma unroll
            for (int i = 0; i < n; ++i)
                v[i] = (kc & (1 << lvl)) ? v[2 * i + 1] : v[2 * i];
        }
        float acc = v[0];
        // V = V*(1-spk)*decay + d + acc  (bit-exact: spk in {0,1})
        float Vr = sp ? 0.0f : V;
        float bb = __fmul_rn(Vr, decay);
        float cc = __fadd_rn(bb, d);
        V = __fadd_rn(cc, acc);
        float sv = __fadd_rn(V, thr);
        sp = sv > 0.0f;              // heaviside(0)=0 -> strict >
        mask = __ballot(sp);
        bits |= sp ? bit : 0u;
    };

    for (int b = 0; b < NBLK; b += 2) {
        // prefetch block b+1 while computing block b
#pragma unroll
        for (int k = 0; k < 32; ++k)
            bufB[k] = dp[((size_t)(b + 1) * 32 + k) * SUB_NO];
        bits = 0u;
#pragma unroll
        for (int k = 0; k < 32; ++k) STEP(bufA[k], 1u << k);
        pw[(size_t)b * SUB_NO] = bits;

        // prefetch block b+2 while computing block b+1
#pragma unroll
        for (int k = 0; k < 32; ++k)
            bufA[k] = dp[((size_t)(b + 2) * 32 + k) * SUB_NO];
        bits = 0u;
#pragma unroll
        for (int k = 0; k < 32; ++k) STEP(bufB[k], 1u << k);
        pw[(size_t)(b + 1) * SUB_NO] = bits;
    }
}

// ---------------- K2 general fallback: any prop / any density ----------------
__device__ void scan_slow(const float* drive, unsigned int* packed,
                          unsigned long long rowmask, const float* prop_l,
                          float decay, float thr, int s) {
    float V = 0.0f;
    bool sp = false;
    unsigned long long mask = 0ull;
    for (int b = 0; b < NBLK; ++b) {
        unsigned int bits = 0u;
        for (int k = 0; k < 32; ++k) {
            int t = b * 32 + k;
            float d = drive[(size_t)t * SUB_NO + s];
            unsigned long long m = mask & rowmask;
            float acc = 0.0f;
            for (int j = 0; j < SUB_NO; ++j) {
                float c = ((m >> j) & 1ull) ? prop_l[j] : 0.0f;
                acc = __fadd_rn(acc, c);
            }
            float Vr = sp ? 0.0f : V;
            float bb = __fmul_rn(Vr, decay);
            float cc = __fadd_rn(bb, d);
            V = __fadd_rn(cc, acc);
            float sv = __fadd_rn(V, thr);
            sp = sv > 0.0f;
            mask = __ballot(sp);
            bits |= sp ? (1u << k) : 0u;
        }
        packed[(size_t)b * SUB_NO + s] = bits;
    }
}

__global__ void __launch_bounds__(64, 1)
scan_kernel(const float* drive, const float* __restrict__ Cden,
            const float* __restrict__ decay_raw, const float* __restrict__ thr_raw,
            const float* __restrict__ prop_raw, unsigned int* packed) {
    __shared__ float prop_l[SUB_NO];
    int s = threadIdx.x;
    prop_l[s] = (float)exp((double)prop_raw[s]);
    __syncthreads();
    float myp = prop_l[s];

    float em = (float)exp(-(double)decay_raw[s]);
    float den = __fadd_rn(1.0f, em);
    float decay = (float)(1.0 / (double)den);
    float thr = -(float)exp((double)thr_raw[s]);

    unsigned long long rowmask = 0ull;
    for (int j = 0; j < SUB_NO; ++j)
        if (Cden[(size_t)s * SUB_NO + j] != 0.0f) rowmask |= (1ull << j);

    float p0 = prop_l[0];
    bool uni = __all(myp == p0);
    int maxk = (int)__popcll(rowmask);
    for (int off = 32; off; off >>= 1) {
        int o = __shfl_xor(maxk, off);
        maxk = maxk > o ? maxk : o;
    }

    if (uni && maxk <= 7)       scan_fast<3>(drive, packed, rowmask, p0, decay, thr, s);
    else if (uni && maxk <= 15) scan_fast<4>(drive, packed, rowmask, p0, decay, thr, s);
    else                        scan_slow(drive, packed, rowmask, prop_l, decay, thr, s);
}

// ---------------- K3: expand packed bits -> f32 spk_out ----------------
__global__ void expand_kernel(const unsigned int* __restrict__ packed,
                              float* __restrict__ spk_out) {
    int idx = blockIdx.x * 256 + threadIdx.x;   // 640000 total
    int t = idx >> 6, s = idx & 63;
    unsigned int w = packed[(size_t)(t >> 5) * SUB_NO + s];
    spk_out[idx] = (float)((w >> (t & 31)) & 1u);
}

// ---------------- K4: 201-tap conv of subunit-0 spikes ----------------
__global__ void conv_kernel(const unsigned int* __restrict__ packed,
                            float* __restrict__ out) {
    __shared__ float kern_s[KERN_LEN];
    __shared__ float x_s[256 + 2 * PAD];
    int tid = threadIdx.x;
    int t0 = blockIdx.x * 256;

    float e2 = (float)exp(2.0);
    float e075 = (float)exp(0.75);
    for (int m = tid; m < KERN_LEN; m += 256) {
        float tt = (float)m / e2;
        kern_s[m] = __fmul_rn(__fmul_rn(tt, expf(-tt)), e075);
    }
    for (int k = tid; k < 256 + 2 * PAD; k += 256) {
        int idx = t0 - PAD + k;
        float xv = 0.0f;
        if (idx >= 0 && idx < T_DATA) {
            unsigned int w = packed[(size_t)(idx >> 5) * SUB_NO];
            xv = (float)((w >> (idx & 31)) & 1u);
        }
        x_s[k] = xv;
    }
    __syncthreads();

    int t = t0 + tid;
    if (t < T_DATA) {
        float acc = 0.0f;
        for (int m = 0; m < KERN_LEN; ++m)
            acc += kern_s[m] * x_s[tid + 2 * PAD - m];
        out[t] = acc;
    }
}

extern "C" void kernel_launch(void* const* d_in, const int* in_sizes, int n_in,
                              void* d_out, int out_size, void* d_ws, size_t ws_size,
                              hipStream_t stream) {
    const float* S_e      = (const float*)d_in[0];
    const float* S_i      = (const float*)d_in[1];
    const float* C_den    = (const float*)d_in[2];
    const float* C_syn_e  = (const float*)d_in[3];
    const float* C_syn_i  = (const float*)d_in[4];
    const float* w_raw    = (const float*)d_in[5];
    const float* dec_raw  = (const float*)d_in[6];
    const float* thr_raw  = (const float*)d_in[7];
    const float* prop_raw = (const float*)d_in[8];

    float* out = (float*)d_out;               // [0,10000) final, [10000,650000) spk_out
    float* ws = (float*)d_ws;
    float* drive = ws;                         // 640000 floats (+ over-read slack)
    int*   ae    = (int*)(ws + 640000);        // 2000 ints
    int*   ai    = (int*)(ws + 642000);        // 500 ints

    // packed spike words: separate region if ws allows, else alias drive (safe).
    size_t need_bytes = (size_t)(642500 + NBLK * SUB_NO) * 4;
    unsigned int* packed = (ws_size >= need_bytes)
                               ? (unsigned int*)(ws + 642500)
                               : (unsigned int*)ws;

    assign_kernel<<<(E_NO + I_NO + 255) / 256, 256, 0, stream>>>(C_syn_e, C_syn_i, ae, ai);
    drive_kernel<<<T_DATA, 256, 0, stream>>>(S_e, S_i, w_raw, ae, ai, drive);
    scan_kernel<<<1, 64, 0, stream>>>(drive, C_den, dec_raw, thr_raw, prop_raw, packed);
    expand_kernel<<<T_DATA * SUB_NO / 256, 256, 0, stream>>>(packed, out + T_DATA);
    conv_kernel<<<(T_DATA + 255) / 256, 256, 0, stream>>>(packed, out);
}

// Round 3
// 552.163 us; speedup vs baseline: 3.6091x; 1.1055x over previous
//
#include <hip/hip_runtime.h>
#include <math.h>

#define T_DATA 10000
#define E_NO 2000
#define I_NO 500
#define SUB_NO 64
#define KERN_LEN 201
#define PAD 100
#define NBLK 314              // 314*32 = 10048 >= 10000 steps (tail garbage unread)

// register-only lane select on an explicit 64-bit lane mask (sgpr pair).
// dst = mask[lane] ? b1 : a0.  Pure VALU, all deps via operands.
__device__ __forceinline__ float sel_f(float a0, float b1, unsigned long long m) {
    float r;
    asm("v_cndmask_b32 %0, %1, %2, %3" : "=v"(r) : "v"(a0), "v"(b1), "s"(m));
    return r;
}
__device__ __forceinline__ unsigned int sel_u(unsigned int a0, unsigned int b1,
                                              unsigned long long m) {
    unsigned int r;
    asm("v_cndmask_b32 %0, %1, %2, %3" : "=v"(r) : "v"(a0), "v"(b1), "s"(m));
    return r;
}

// ---------------- K0: extract one-hot assignments ----------------
__global__ void assign_kernel(const float* __restrict__ Ce, const float* __restrict__ Ci,
                              int* __restrict__ ae, int* __restrict__ ai) {
    int idx = blockIdx.x * 256 + threadIdx.x;
    if (idx < E_NO) {
        int a = 0;
        for (int s = 0; s < SUB_NO; ++s)
            if (Ce[(size_t)s * E_NO + idx] != 0.0f) a = s;
        ae[idx] = a;
    } else if (idx < E_NO + I_NO) {
        int i = idx - E_NO;
        int a = 0;
        for (int s = 0; s < SUB_NO; ++s)
            if (Ci[(size_t)s * I_NO + i] != 0.0f) a = s;
        ai[i] = a;
    }
}

// ---------------- K1: drive[t][s] = cnt_e*we[s] + cnt_i*wi[s] ----------------
__global__ void drive_kernel(const float* __restrict__ Se, const float* __restrict__ Si,
                             const float* __restrict__ wraw,
                             const int* __restrict__ ae, const int* __restrict__ ai,
                             float* __restrict__ drive) {
    __shared__ float be[SUB_NO];
    __shared__ float bi[SUB_NO];
    int t = blockIdx.x;
    int tid = threadIdx.x;
    if (tid < SUB_NO) { be[tid] = 0.0f; bi[tid] = 0.0f; }
    __syncthreads();
    // rows are 8000B / 2000B -> 16B aligned; counts exact ints, add order free
    const float4* se4 = (const float4*)(Se + (size_t)t * E_NO);
    for (int e4 = tid; e4 < E_NO / 4; e4 += 256) {
        float4 v = se4[e4];
        int b = e4 * 4;
        if (v.x != 0.0f) atomicAdd(&be[ae[b + 0]], 1.0f);
        if (v.y != 0.0f) atomicAdd(&be[ae[b + 1]], 1.0f);
        if (v.z != 0.0f) atomicAdd(&be[ae[b + 2]], 1.0f);
        if (v.w != 0.0f) atomicAdd(&be[ae[b + 3]], 1.0f);
    }
    const float4* si4 = (const float4*)(Si + (size_t)t * I_NO);
    for (int i4 = tid; i4 < I_NO / 4; i4 += 256) {
        float4 v = si4[i4];
        int b = i4 * 4;
        if (v.x != 0.0f) atomicAdd(&bi[ai[b + 0]], 1.0f);
        if (v.y != 0.0f) atomicAdd(&bi[ai[b + 1]], 1.0f);
        if (v.z != 0.0f) atomicAdd(&bi[ai[b + 2]], 1.0f);
        if (v.w != 0.0f) atomicAdd(&bi[ai[b + 3]], 1.0f);
    }
    __syncthreads();
    if (tid < SUB_NO) {
        float we = (float)exp((double)wraw[2 * tid]);
        float wi = -(float)exp((double)wraw[2 * tid + 1]);
        drive[(size_t)t * SUB_NO + tid] =
            __fadd_rn(__fmul_rn(be[tid], we), __fmul_rn(bi[tid], wi));
    }
}

// ---------------- K2 fast path A: acc == RN(kc*p) (runtime-verified) ----------------
__device__ void scan_lin(const float* __restrict__ drive, unsigned int* __restrict__ packed,
                         unsigned long long rowmask, float p0,
                         float decay, float thrpos, int s) {
    float V = 0.0f;
    unsigned long long mask = 0ull;   // ballot of spikes; doubles as per-lane sp bit
    const float* dp = drive + s;
    unsigned int* pw = packed + s;
    unsigned int row_lo = (unsigned int)rowmask;
    unsigned int row_hi = (unsigned int)(rowmask >> 32);
    float zerof = 0.0f;
    unsigned int bits = 0u;

    float bufA[32], bufB[32];
#pragma unroll
    for (int k = 0; k < 32; ++k) bufA[k] = dp[(size_t)k * SUB_NO];

    auto STEP = [&](float d, unsigned int bitk) {
        unsigned int kc = __popc(((unsigned int)mask) & row_lo)
                        + __popc(((unsigned int)(mask >> 32)) & row_hi);
        float acc = __fmul_rn((float)kc, p0);           // == sequential sum (verified)
        float Vr = sel_f(V, zerof, mask);               // V*(1-spk), exact
        float bb = __fmul_rn(Vr, decay);
        float cc = __fadd_rn(bb, d);
        V = __fadd_rn(cc, acc);
        // RN(V+thr)>0  <=>  V>|thr|  (Sterbenz) -> one cmp serves sp+ballot
        mask = __ballot(V > thrpos);
        bits = sel_u(bits, bits | bitk, mask);
    };

    for (int b = 0; b < NBLK; b += 2) {
#pragma unroll
        for (int k = 0; k < 32; ++k) bufB[k] = dp[((size_t)(b + 1) * 32 + k) * SUB_NO];
        bits = 0u;
#pragma unroll
        for (int k = 0; k < 32; ++k) STEP(bufA[k], 1u << k);
        pw[(size_t)b * SUB_NO] = bits;
#pragma unroll
        for (int k = 0; k < 32; ++k) bufA[k] = dp[((size_t)(b + 2) * 32 + k) * SUB_NO];
        bits = 0u;
#pragma unroll
        for (int k = 0; k < 32; ++k) STEP(bufB[k], 1u << k);
        pw[(size_t)(b + 1) * SUB_NO] = bits;
    }
}

// ---------------- K2 fast path B: uniform p, table via hoisted-mask cndmask tree ----
template<int KBITS>
__device__ void scan_tree(const float* __restrict__ drive, unsigned int* __restrict__ packed,
                          unsigned long long rowmask, float p0,
                          float decay, float thrpos, int s) {
    constexpr int NT = 1 << KBITS;
    float tbl[NT];
    {
        float f = 0.0f;
#pragma unroll
        for (int i = 0; i < NT; ++i) { tbl[i] = f; f = __fadd_rn(f, p0); }
    }
    float V = 0.0f;
    unsigned long long mask = 0ull;
    const float* dp = drive + s;
    unsigned int* pw = packed + s;
    unsigned int row_lo = (unsigned int)rowmask;
    unsigned int row_hi = (unsigned int)(rowmask >> 32);
    float zerof = 0.0f;
    unsigned int bits = 0u;

    float bufA[32], bufB[32];
#pragma unroll
    for (int k = 0; k < 32; ++k) bufA[k] = dp[(size_t)k * SUB_NO];

    auto STEP = [&](float d, unsigned int bitk) {
        unsigned int kc = __popc(((unsigned int)mask) & row_lo)
                        + __popc(((unsigned int)(mask >> 32)) & row_hi);
        unsigned long long lm[KBITS];
#pragma unroll
        for (int l = 0; l < KBITS; ++l) lm[l] = __ballot(kc & (1u << l));
        float v[NT / 2];
#pragma unroll
        for (int i = 0; i < NT / 2; ++i) v[i] = sel_f(tbl[2 * i], tbl[2 * i + 1], lm[0]);
#pragma unroll
        for (int l = 1; l < KBITS; ++l) {
            const int n = NT >> (l + 1);
#pragma unroll
            for (int i = 0; i < n; ++i) v[i] = sel_f(v[2 * i], v[2 * i + 1], lm[l]);
        }
        float acc = v[0];
        float Vr = sel_f(V, zerof, mask);
        float bb = __fmul_rn(Vr, decay);
        float cc = __fadd_rn(bb, d);
        V = __fadd_rn(cc, acc);
        mask = __ballot(V > thrpos);
        bits = sel_u(bits, bits | bitk, mask);
    };

    for (int b = 0; b < NBLK; b += 2) {
#pragma unroll
        for (int k = 0; k < 32; ++k) bufB[k] = dp[((size_t)(b + 1) * 32 + k) * SUB_NO];
        bits = 0u;
#pragma unroll
        for (int k = 0; k < 32; ++k) STEP(bufA[k], 1u << k);
        pw[(size_t)b * SUB_NO] = bits;
#pragma unroll
        for (int k = 0; k < 32; ++k) bufA[k] = dp[((size_t)(b + 2) * 32 + k) * SUB_NO];
        bits = 0u;
#pragma unroll
        for (int k = 0; k < 32; ++k) STEP(bufB[k], 1u << k);
        pw[(size_t)(b + 1) * SUB_NO] = bits;
    }
}

// ---------------- K2 general fallback: any prop / any density ----------------
__device__ void scan_slow(const float* drive, unsigned int* packed,
                          unsigned long long rowmask, const float* prop_l,
                          float decay, float thr, int s) {
    float V = 0.0f;
    bool sp = false;
    unsigned long long mask = 0ull;
    for (int b = 0; b < NBLK; ++b) {
        unsigned int bits = 0u;
        for (int k = 0; k < 32; ++k) {
            int t = b * 32 + k;
            float d = drive[(size_t)t * SUB_NO + s];
            unsigned long long m = mask & rowmask;
            float acc = 0.0f;
            for (int j = 0; j < SUB_NO; ++j) {
                float c = ((m >> j) & 1ull) ? prop_l[j] : 0.0f;
                acc = __fadd_rn(acc, c);
            }
            float Vr = sp ? 0.0f : V;
            float bb = __fmul_rn(Vr, decay);
            float cc = __fadd_rn(bb, d);
            V = __fadd_rn(cc, acc);
            float sv = __fadd_rn(V, thr);
            sp = sv > 0.0f;
            mask = __ballot(sp);
            bits |= sp ? (1u << k) : 0u;
        }
        packed[(size_t)b * SUB_NO + s] = bits;
    }
}

__global__ void __launch_bounds__(64, 1)
scan_kernel(const float* drive, const float* __restrict__ Cden,
            const float* __restrict__ decay_raw, const float* __restrict__ thr_raw,
            const float* __restrict__ prop_raw, unsigned int* packed) {
    __shared__ float prop_l[SUB_NO];
    int s = threadIdx.x;
    prop_l[s] = (float)exp((double)prop_raw[s]);
    __syncthreads();
    float myp = prop_l[s];

    float em = (float)exp(-(double)decay_raw[s]);
    float den = __fadd_rn(1.0f, em);
    float decay = (float)(1.0 / (double)den);
    float thrpos = (float)exp((double)thr_raw[s]);   // |thr|
    float thr = -thrpos;

    unsigned long long rowmask = 0ull;
    for (int j = 0; j < SUB_NO; ++j)
        if (Cden[(size_t)s * SUB_NO + j] != 0.0f) rowmask |= (1ull << j);

    float p0 = prop_l[0];
    bool uni = __all(myp == p0);
    int maxk = (int)__popcll(rowmask);
    for (int off = 32; off; off >>= 1) {
        int o = __shfl_xor(maxk, off);
        maxk = maxk > o ? maxk : o;
    }

    // linearity check: lane k verifies seq-sum(k copies of p) == RN(k*p)
    float seqk = 0.0f;
    for (int i = 0; i < s; ++i) seqk = __fadd_rn(seqk, p0);
    bool lok = (s > maxk) || (seqk == __fmul_rn((float)s, p0));
    bool uselin = uni && __all(lok);

    if (uselin)                 scan_lin(drive, packed, rowmask, p0, decay, thrpos, s);
    else if (uni && maxk <= 7)  scan_tree<3>(drive, packed, rowmask, p0, decay, thrpos, s);
    else if (uni && maxk <= 15) scan_tree<4>(drive, packed, rowmask, p0, decay, thrpos, s);
    else if (uni && maxk <= 31) scan_tree<5>(drive, packed, rowmask, p0, decay, thrpos, s);
    else                        scan_slow(drive, packed, rowmask, prop_l, decay, thr, s);
}

// ---------------- K3: expand packed bits -> f32 spk_out ----------------
__global__ void expand_kernel(const unsigned int* __restrict__ packed,
                              float* __restrict__ spk_out) {
    int idx = blockIdx.x * 256 + threadIdx.x;   // 640000 total
    int t = idx >> 6, s = idx & 63;
    unsigned int w = packed[(size_t)(t >> 5) * SUB_NO + s];
    spk_out[idx] = (float)((w >> (t & 31)) & 1u);
}

// ---------------- K4: 201-tap conv of subunit-0 spikes ----------------
__global__ void conv_kernel(const unsigned int* __restrict__ packed,
                            float* __restrict__ out) {
    __shared__ float kern_s[KERN_LEN];
    __shared__ float x_s[256 + 2 * PAD];
    int tid = threadIdx.x;
    int t0 = blockIdx.x * 256;

    float e2 = (float)exp(2.0);
    float e075 = (float)exp(0.75);
    for (int m = tid; m < KERN_LEN; m += 256) {
        float tt = (float)m / e2;
        kern_s[m] = __fmul_rn(__fmul_rn(tt, expf(-tt)), e075);
    }
    for (int k = tid; k < 256 + 2 * PAD; k += 256) {
        int idx = t0 - PAD + k;
        float xv = 0.0f;
        if (idx >= 0 && idx < T_DATA) {
            unsigned int w = packed[(size_t)(idx >> 5) * SUB_NO];
            xv = (float)((w >> (idx & 31)) & 1u);
        }
        x_s[k] = xv;
    }
    __syncthreads();

    int t = t0 + tid;
    if (t < T_DATA) {
        float acc = 0.0f;
        for (int m = 0; m < KERN_LEN; ++m)
            acc += kern_s[m] * x_s[tid + 2 * PAD - m];
        out[t] = acc;
    }
}

extern "C" void kernel_launch(void* const* d_in, const int* in_sizes, int n_in,
                              void* d_out, int out_size, void* d_ws, size_t ws_size,
                              hipStream_t stream) {
    const float* S_e      = (const float*)d_in[0];
    const float* S_i      = (const float*)d_in[1];
    const float* C_den    = (const float*)d_in[2];
    const float* C_syn_e  = (const float*)d_in[3];
    const float* C_syn_i  = (const float*)d_in[4];
    const float* w_raw    = (const float*)d_in[5];
    const float* dec_raw  = (const float*)d_in[6];
    const float* thr_raw  = (const float*)d_in[7];
    const float* prop_raw = (const float*)d_in[8];

    float* out = (float*)d_out;               // [0,10000) final, [10000,650000) spk_out
    float* ws = (float*)d_ws;
    float* drive = ws;                         // 640000 floats (+ over-read slack)
    int*   ae    = (int*)(ws + 640000);        // 2000 ints
    int*   ai    = (int*)(ws + 642000);        // 500 ints

    size_t need_bytes = (size_t)(642500 + NBLK * SUB_NO) * 4;
    unsigned int* packed = (ws_size >= need_bytes)
                               ? (unsigned int*)(ws + 642500)
                               : (unsigned int*)ws;

    assign_kernel<<<(E_NO + I_NO + 255) / 256, 256, 0, stream>>>(C_syn_e, C_syn_i, ae, ai);
    drive_kernel<<<T_DATA, 256, 0, stream>>>(S_e, S_i, w_raw, ae, ai, drive);
    scan_kernel<<<1, 64, 0, stream>>>(drive, C_den, dec_raw, thr_raw, prop_raw, packed);
    expand_kernel<<<T_DATA * SUB_NO / 256, 256, 0, stream>>>(packed, out + T_DATA);
    conv_kernel<<<(T_DATA + 255) / 256, 256, 0, stream>>>(packed, out);
}